// Round 1
// baseline (2073.473 us; speedup 1.0000x reference)
//
#include <hip/hip_runtime.h>
#include <math.h>

// ---------------- device helpers ----------------
__device__ __forceinline__ float gelu_exact(float x) {
    return 0.5f * x * (1.0f + erff(x * 0.70710678118654752f));
}
__device__ __forceinline__ float softplus_f(float x) {
    return (x > 20.0f) ? x : log1pf(expf(x));
}
__device__ __forceinline__ float sigmoid_f(float x) {
    return 1.0f / (1.0f + __expf(-x));
}

// ---------------- GEMM: C[m,n] = act(sum_k A[m,k]*W[n,k] + bias[n]) + res[m,n] ----
// A: M x K (row stride lda), W: N x K (packed), C: M x N
// act: 0 = none, 1 = gelu, 2 = softplus
__global__ __launch_bounds__(256)
void gemm_bt(const float* __restrict__ A, int lda,
             const float* __restrict__ W,
             const float* __restrict__ bias,
             const float* res,
             float* C,
             int M, int N, int K, int act)
{
    __shared__ float As[16][65];
    __shared__ float Ws[16][65];
    const int tid = threadIdx.x;
    const int tx = tid & 15, ty = tid >> 4;
    const int m0 = blockIdx.y * 64, n0 = blockIdx.x * 64;

    float acc[4][4] = {};

    for (int k0 = 0; k0 < K; k0 += 16) {
        #pragma unroll
        for (int i = 0; i < 4; i++) {
            int idx = tid + i * 256;
            int mm = idx >> 4, kk = idx & 15;
            As[kk][mm] = A[(size_t)(m0 + mm) * lda + (k0 + kk)];
        }
        #pragma unroll
        for (int i = 0; i < 4; i++) {
            int idx = tid + i * 256;
            int nn = idx >> 4, kk = idx & 15;
            int n = n0 + nn;
            Ws[kk][nn] = (n < N) ? W[(size_t)n * K + (k0 + kk)] : 0.0f;
        }
        __syncthreads();
        #pragma unroll
        for (int kk = 0; kk < 16; kk++) {
            float a[4], b[4];
            #pragma unroll
            for (int i = 0; i < 4; i++) a[i] = As[kk][ty + 16 * i];
            #pragma unroll
            for (int j = 0; j < 4; j++) b[j] = Ws[kk][tx + 16 * j];
            #pragma unroll
            for (int i = 0; i < 4; i++)
                #pragma unroll
                for (int j = 0; j < 4; j++)
                    acc[i][j] += a[i] * b[j];
        }
        __syncthreads();
    }

    #pragma unroll
    for (int i = 0; i < 4; i++) {
        int m = m0 + ty + 16 * i;
        #pragma unroll
        for (int j = 0; j < 4; j++) {
            int n = n0 + tx + 16 * j;
            if (n < N) {
                float v = acc[i][j];
                if (bias) v += bias[n];
                if (act == 1) v = gelu_exact(v);
                else if (act == 2) v = softplus_f(v);
                if (res) v += res[(size_t)m * N + n];
                C[(size_t)m * N + n] = v;
            }
        }
    }
}

// ---------------- LayerNorm over last dim (=256), optional GELU ----------------
__global__ __launch_bounds__(256)
void ln_act(const float* __restrict__ in, const float* __restrict__ g,
            const float* __restrict__ b, float* __restrict__ out, int act)
{
    __shared__ float s1[256];
    __shared__ float s2[256];
    const int row = blockIdx.x, tid = threadIdx.x;
    float v = in[(size_t)row * 256 + tid];
    s1[tid] = v;
    s2[tid] = v * v;
    __syncthreads();
    for (int off = 128; off > 0; off >>= 1) {
        if (tid < off) { s1[tid] += s1[tid + off]; s2[tid] += s2[tid + off]; }
        __syncthreads();
    }
    float mu = s1[0] * (1.0f / 256.0f);
    float var = s2[0] * (1.0f / 256.0f) - mu * mu;
    float o = (v - mu) * rsqrtf(var + 1e-5f) * g[tid] + b[tid];
    if (act) o = gelu_exact(o);
    out[(size_t)row * 256 + tid] = o;
}

// ---------------- causal depthwise conv (D_CONV=4) + bias + SiLU ----------------
// u part = xz[..., 0:512] of xz (BL x 1024); output uc: BL x 512
__global__ void conv_silu(const float* __restrict__ xz, const float* __restrict__ cw,
                          const float* __restrict__ cb, float* __restrict__ uc)
{
    int idx = blockIdx.x * blockDim.x + threadIdx.x;
    if (idx >= 4096 * 512) return;
    int d = idx & 511;
    int bt = idx >> 9;
    int t = bt & 1023, b = bt >> 10;
    float acc = cb[d];
    #pragma unroll
    for (int k = 0; k < 4; k++) {
        int tt = t - 3 + k;
        if (tt >= 0) acc += xz[((size_t)(b * 1024 + tt)) * 1024 + d] * cw[d * 4 + k];
    }
    uc[idx] = acc * sigmoid_f(acc);
}

// ---------------- selective scan ----------------
// one wave per block; block handles 4 d's x 16 states (lane = dsub*16 + s)
// fuses y = (scan + u*D) * silu(z)
__global__ __launch_bounds__(64)
void scan_kernel(const float* __restrict__ delta, const float* __restrict__ uc,
                 const float* __restrict__ xdbc, const float* __restrict__ xz,
                 const float* __restrict__ A_log, const float* __restrict__ Dp,
                 float* __restrict__ y)
{
    const int bid = blockIdx.x;          // 0..511
    const int b = bid >> 7;              // batch
    const int d0 = (bid & 127) * 4;
    const int lane = threadIdx.x;
    const int dsub = lane >> 4, s = lane & 15;
    const int d = d0 + dsub;

    const float Acoef = -__expf(A_log[d * 16 + s]);
    const float Dd = Dp[d];

    const size_t base = (size_t)b * 1024;
    const float* pd = delta + base * 512 + d;
    const float* pu = uc    + base * 512 + d;
    const float* pB = xdbc  + base * 48 + 16 + s;
    const float* pC = xdbc  + base * 48 + 32 + s;
    const float* pz = xz    + base * 1024 + 512 + d;
    float*       py = y     + base * 512 + d;

    float st = 0.0f;
    for (int t = 0; t < 1024; t++) {
        float dt = *pd;
        float ut = *pu;
        float Bt = *pB;
        float Ct = *pC;
        float dA = __expf(dt * Acoef);
        st = st * dA + dt * ut * Bt;
        float part = st * Ct;
        part += __shfl_xor(part, 8, 16);
        part += __shfl_xor(part, 4, 16);
        part += __shfl_xor(part, 2, 16);
        part += __shfl_xor(part, 1, 16);
        if (s == 0) {
            float zt = *pz;
            py[0] = (part + ut * Dd) * (zt * sigmoid_f(zt));
        }
        pd += 512; pu += 512; pB += 48; pC += 48; pz += 1024; py += 512;
    }
}

// ---------------- l2 loss ----------------
__global__ void zero_one(float* p) { if (threadIdx.x == 0 && blockIdx.x == 0) *p = 0.0f; }

__global__ __launch_bounds__(256)
void l2_kernel(const float* __restrict__ h, float* out)
{
    __shared__ float s1[256];
    const int row = blockIdx.x, tid = threadIdx.x;
    float v = h[(size_t)row * 256 + tid];
    s1[tid] = v * v;
    __syncthreads();
    for (int off = 128; off > 0; off >>= 1) {
        if (tid < off) s1[tid] += s1[tid + off];
        __syncthreads();
    }
    if (tid == 0) atomicAdd(out, sqrtf(s1[0]) * (0.01f / 4096.0f));
}

// ---------------- launcher ----------------
extern "C" void kernel_launch(void* const* d_in, const int* in_sizes, int n_in,
                              void* d_out, int out_size, void* d_ws, size_t ws_size,
                              hipStream_t stream)
{
    const float* x      = (const float*)d_in[0];
    const float* in_w   = (const float*)d_in[1];
    const float* in_b   = (const float*)d_in[2];
    const float* ln_g   = (const float*)d_in[3];
    const float* ln_b   = (const float*)d_in[4];
    const float* blk_ng  = (const float*)d_in[5];
    const float* blk_nb  = (const float*)d_in[6];
    const float* blk_ipw = (const float*)d_in[7];
    const float* blk_cw  = (const float*)d_in[8];
    const float* blk_cb  = (const float*)d_in[9];
    const float* blk_xpw = (const float*)d_in[10];
    const float* blk_dtw = (const float*)d_in[11];
    const float* blk_dtb = (const float*)d_in[12];
    const float* blk_Alog= (const float*)d_in[13];
    const float* blk_D   = (const float*)d_in[14];
    const float* blk_opw = (const float*)d_in[15];
    const float* op_w   = (const float*)d_in[16];
    const float* op_b   = (const float*)d_in[17];
    const float* cls_w  = (const float*)d_in[18];
    const float* cls_b  = (const float*)d_in[19];
    float* out = (float*)d_out;

    const int BL = 4096;
    float* ws = (float*)d_ws;
    float* hn   = ws;                    // BL*256
    float* h0   = hn + (size_t)BL * 256; // BL*256
    float* h2   = h0 + (size_t)BL * 256; // BL*256
    float* xz   = h2 + (size_t)BL * 256; // BL*1024
    float* uc   = xz + (size_t)BL * 1024;// BL*512
    float* xdbc = uc + (size_t)BL * 512; // BL*48
    float* dlt  = xdbc + (size_t)BL * 48;// BL*512
    float* yb   = dlt + (size_t)BL * 512;// BL*512

    dim3 blk(256);

    // 1. hn = x @ in_w.T + in_b   (M=4096, N=256, K=768)
    gemm_bt<<<dim3(256 / 64, BL / 64), blk, 0, stream>>>(x, 768, in_w, in_b, nullptr, hn, BL, 256, 768, 0);
    // 2. h0 = gelu(LN(hn))
    ln_act<<<BL, 256, 0, stream>>>(hn, ln_g, ln_b, h0, 1);

    for (int l = 0; l < 2; l++) {
        const float* ng   = blk_ng  + l * 256;
        const float* nb   = blk_nb  + l * 256;
        const float* ipw  = blk_ipw + (size_t)l * 1024 * 256;
        const float* cw   = blk_cw  + (size_t)l * 512 * 4;
        const float* cb   = blk_cb  + l * 512;
        const float* xpw  = blk_xpw + (size_t)l * 48 * 512;
        const float* dtw  = blk_dtw + (size_t)l * 512 * 16;
        const float* dtb  = blk_dtb + l * 512;
        const float* Alog = blk_Alog+ (size_t)l * 512 * 16;
        const float* Dl   = blk_D   + l * 512;
        const float* opw  = blk_opw + (size_t)l * 256 * 512;

        // hn = LN(h0)
        ln_act<<<BL, 256, 0, stream>>>(h0, ng, nb, hn, 0);
        // xz = hn @ ipw.T   (N=1024, K=256)
        gemm_bt<<<dim3(1024 / 64, BL / 64), blk, 0, stream>>>(hn, 256, ipw, nullptr, nullptr, xz, BL, 1024, 256, 0);
        // uc = silu(conv(u) + cb)
        conv_silu<<<(BL * 512 + 255) / 256, blk, 0, stream>>>(xz, cw, cb, uc);
        // xdbc = uc @ xpw.T  (N=48, K=512)
        gemm_bt<<<dim3(1, BL / 64), blk, 0, stream>>>(uc, 512, xpw, nullptr, nullptr, xdbc, BL, 48, 512, 0);
        // dlt = softplus(dt @ dtw.T + dtb)  (A = xdbc cols 0..15, lda=48; N=512, K=16)
        gemm_bt<<<dim3(512 / 64, BL / 64), blk, 0, stream>>>(xdbc, 48, dtw, dtb, nullptr, dlt, BL, 512, 16, 2);
        // scan -> yb  (fused +u*D and *silu(z))
        scan_kernel<<<512, 64, 0, stream>>>(dlt, uc, xdbc, xz, Alog, Dl, yb);
        // h0 = h0 + yb @ opw.T  (N=256, K=512)
        gemm_bt<<<dim3(256 / 64, BL / 64), blk, 0, stream>>>(yb, 512, opw, nullptr, h0, h0, BL, 256, 512, 0);
    }

    // h2 = gelu(h0 @ op_w.T + op_b)
    gemm_bt<<<dim3(256 / 64, BL / 64), blk, 0, stream>>>(h0, 256, op_w, op_b, nullptr, h2, BL, 256, 256, 1);
    // logits = h2 @ cls_w.T + cls_b  -> d_out
    gemm_bt<<<dim3(128 / 64, BL / 64), blk, 0, stream>>>(h2, 256, cls_w, cls_b, nullptr, out, BL, 128, 256, 0);
    // l2 scalar
    zero_one<<<1, 1, 0, stream>>>(out + (size_t)BL * 128);
    l2_kernel<<<BL, 256, 0, stream>>>(h2, out + (size_t)BL * 128);
}

// Round 2
// 884.538 us; speedup vs baseline: 2.3441x; 2.3441x over previous
//
#include <hip/hip_runtime.h>
#include <math.h>

// ---------------- device helpers ----------------
__device__ __forceinline__ float gelu_exact(float x) {
    return 0.5f * x * (1.0f + erff(x * 0.70710678118654752f));
}
__device__ __forceinline__ float softplus_f(float x) {
    return (x > 20.0f) ? x : log1pf(expf(x));
}
__device__ __forceinline__ float sigmoid_f(float x) {
    return 1.0f / (1.0f + __expf(-x));
}

// ---------------- GEMM: C[m,n] = act(sum_k A[m,k]*W[n,k] + bias[n]) + res[m,n] ----
// A: M x K (row stride lda), W: N x K (packed), C: M x N
// act: 0 = none, 1 = gelu, 2 = softplus
__global__ __launch_bounds__(256)
void gemm_bt(const float* __restrict__ A, int lda,
             const float* __restrict__ W,
             const float* __restrict__ bias,
             const float* res,
             float* C,
             int M, int N, int K, int act)
{
    __shared__ float As[16][65];
    __shared__ float Ws[16][65];
    const int tid = threadIdx.x;
    const int tx = tid & 15, ty = tid >> 4;
    const int m0 = blockIdx.y * 64, n0 = blockIdx.x * 64;

    float acc[4][4] = {};

    for (int k0 = 0; k0 < K; k0 += 16) {
        #pragma unroll
        for (int i = 0; i < 4; i++) {
            int idx = tid + i * 256;
            int mm = idx >> 4, kk = idx & 15;
            As[kk][mm] = A[(size_t)(m0 + mm) * lda + (k0 + kk)];
        }
        #pragma unroll
        for (int i = 0; i < 4; i++) {
            int idx = tid + i * 256;
            int nn = idx >> 4, kk = idx & 15;
            int n = n0 + nn;
            Ws[kk][nn] = (n < N) ? W[(size_t)n * K + (k0 + kk)] : 0.0f;
        }
        __syncthreads();
        #pragma unroll
        for (int kk = 0; kk < 16; kk++) {
            float a[4], b[4];
            #pragma unroll
            for (int i = 0; i < 4; i++) a[i] = As[kk][ty + 16 * i];
            #pragma unroll
            for (int j = 0; j < 4; j++) b[j] = Ws[kk][tx + 16 * j];
            #pragma unroll
            for (int i = 0; i < 4; i++)
                #pragma unroll
                for (int j = 0; j < 4; j++)
                    acc[i][j] += a[i] * b[j];
        }
        __syncthreads();
    }

    #pragma unroll
    for (int i = 0; i < 4; i++) {
        int m = m0 + ty + 16 * i;
        #pragma unroll
        for (int j = 0; j < 4; j++) {
            int n = n0 + tx + 16 * j;
            if (n < N) {
                float v = acc[i][j];
                if (bias) v += bias[n];
                if (act == 1) v = gelu_exact(v);
                else if (act == 2) v = softplus_f(v);
                if (res) v += res[(size_t)m * N + n];
                C[(size_t)m * N + n] = v;
            }
        }
    }
}

// ---------------- LayerNorm over last dim (=256), optional GELU ----------------
__global__ __launch_bounds__(256)
void ln_act(const float* __restrict__ in, const float* __restrict__ g,
            const float* __restrict__ b, float* __restrict__ out, int act)
{
    __shared__ float s1[256];
    __shared__ float s2[256];
    const int row = blockIdx.x, tid = threadIdx.x;
    float v = in[(size_t)row * 256 + tid];
    s1[tid] = v;
    s2[tid] = v * v;
    __syncthreads();
    for (int off = 128; off > 0; off >>= 1) {
        if (tid < off) { s1[tid] += s1[tid + off]; s2[tid] += s2[tid + off]; }
        __syncthreads();
    }
    float mu = s1[0] * (1.0f / 256.0f);
    float var = s2[0] * (1.0f / 256.0f) - mu * mu;
    float o = (v - mu) * rsqrtf(var + 1e-5f) * g[tid] + b[tid];
    if (act) o = gelu_exact(o);
    out[(size_t)row * 256 + tid] = o;
}

// ---------------- causal depthwise conv (D_CONV=4) + bias + SiLU ----------------
__global__ void conv_silu(const float* __restrict__ xz, const float* __restrict__ cw,
                          const float* __restrict__ cb, float* __restrict__ uc)
{
    int idx = blockIdx.x * blockDim.x + threadIdx.x;
    if (idx >= 4096 * 512) return;
    int d = idx & 511;
    int bt = idx >> 9;
    int t = bt & 1023, b = bt >> 10;
    float acc = cb[d];
    #pragma unroll
    for (int k = 0; k < 4; k++) {
        int tt = t - 3 + k;
        if (tt >= 0) acc += xz[((size_t)(b * 1024 + tt)) * 1024 + d] * cw[d * 4 + k];
    }
    uc[idx] = acc * sigmoid_f(acc);
}

// ---------------- chunked selective scan ----------------
// grid: 512 blocks of 1024 threads. block = (b, d-group of 4).
// wave w (16 per block) handles time chunk [w*64, w*64+64).
// lane = dsub*16 + s  (4 d's x 16 states).
// Phase A: local scan from 0, accumulate cumprod(dA); y_local -> LDS.
// Phase B: wave 0 combines chunk summaries -> per-chunk incoming state.
// Phase C: propagate g = g*dA from incoming state, y += C·g, fuse +u*D, *silu(z).
__global__ __launch_bounds__(1024)
void scan_chunked(const float* __restrict__ delta, const float* __restrict__ uc,
                  const float* __restrict__ xdbc, const float* __restrict__ xz,
                  const float* __restrict__ A_log, const float* __restrict__ Dp,
                  float* __restrict__ y)
{
    __shared__ float aprod_s[16][64];
    __shared__ float sfin_s[16][64];
    __shared__ float sin_s[16][64];
    __shared__ float ylocal[16][64][4];   // [chunk][t_local][dsub]

    const int bid = blockIdx.x;          // 0..511
    const int b = bid >> 7;
    const int d0 = (bid & 127) * 4;
    const int w = threadIdx.x >> 6;      // chunk id 0..15
    const int lane = threadIdx.x & 63;
    const int dsub = lane >> 4, s = lane & 15;
    const int d = d0 + dsub;

    const float Acoef = -__expf(A_log[d * 16 + s]);
    const float Dd = Dp[d];

    const size_t row0 = (size_t)b * 1024 + w * 64;   // global time-row base for this chunk
    const float* pd = delta + row0 * 512 + d;
    const float* pu = uc    + row0 * 512 + d;
    const float* pB = xdbc  + row0 * 48 + 16 + s;
    const float* pC = xdbc  + row0 * 48 + 32 + s;

    // ---- Phase A: local scan ----
    float st = 0.0f, ap = 1.0f;
    #pragma unroll 4
    for (int t = 0; t < 64; t++) {
        float dt = pd[(size_t)t * 512];
        float ut = pu[(size_t)t * 512];
        float Bt = pB[(size_t)t * 48];
        float Ct = pC[(size_t)t * 48];
        float dA = __expf(dt * Acoef);
        st = st * dA + dt * ut * Bt;
        ap *= dA;
        float part = st * Ct;
        part += __shfl_xor(part, 8, 16);
        part += __shfl_xor(part, 4, 16);
        part += __shfl_xor(part, 2, 16);
        part += __shfl_xor(part, 1, 16);
        if (s == 0) ylocal[w][t][dsub] = part;
    }
    aprod_s[w][lane] = ap;
    sfin_s[w][lane] = st;
    __syncthreads();

    // ---- Phase B: chunk-summary scan (wave 0; lane <-> chain 1:1) ----
    if (w == 0) {
        float pre = 0.0f;
        #pragma unroll
        for (int c = 0; c < 16; c++) {
            sin_s[c][lane] = pre;
            pre = sfin_s[c][lane] + aprod_s[c][lane] * pre;
        }
    }
    __syncthreads();

    // ---- Phase C: correction + epilogue ----
    float g = sin_s[w][lane];
    const float* pz = xz + row0 * 1024 + 512 + d;
    float*       py = y  + row0 * 512 + d;
    #pragma unroll 4
    for (int t = 0; t < 64; t++) {
        float dt = pd[(size_t)t * 512];
        float Ct = pC[(size_t)t * 48];
        g *= __expf(dt * Acoef);
        float part = g * Ct;
        part += __shfl_xor(part, 8, 16);
        part += __shfl_xor(part, 4, 16);
        part += __shfl_xor(part, 2, 16);
        part += __shfl_xor(part, 1, 16);
        if (s == 0) {
            float ut = pu[(size_t)t * 512];
            float zt = pz[(size_t)t * 1024];
            float yv = ylocal[w][t][dsub] + part + ut * Dd;
            py[(size_t)t * 512] = yv * (zt * sigmoid_f(zt));
        }
    }
}

// ---------------- l2 loss ----------------
__global__ void zero_one(float* p) { if (threadIdx.x == 0 && blockIdx.x == 0) *p = 0.0f; }

__global__ __launch_bounds__(256)
void l2_kernel(const float* __restrict__ h, float* out)
{
    __shared__ float s1[256];
    const int row = blockIdx.x, tid = threadIdx.x;
    float v = h[(size_t)row * 256 + tid];
    s1[tid] = v * v;
    __syncthreads();
    for (int off = 128; off > 0; off >>= 1) {
        if (tid < off) s1[tid] += s1[tid + off];
        __syncthreads();
    }
    if (tid == 0) atomicAdd(out, sqrtf(s1[0]) * (0.01f / 4096.0f));
}

// ---------------- launcher ----------------
extern "C" void kernel_launch(void* const* d_in, const int* in_sizes, int n_in,
                              void* d_out, int out_size, void* d_ws, size_t ws_size,
                              hipStream_t stream)
{
    const float* x      = (const float*)d_in[0];
    const float* in_w   = (const float*)d_in[1];
    const float* in_b   = (const float*)d_in[2];
    const float* ln_g   = (const float*)d_in[3];
    const float* ln_b   = (const float*)d_in[4];
    const float* blk_ng  = (const float*)d_in[5];
    const float* blk_nb  = (const float*)d_in[6];
    const float* blk_ipw = (const float*)d_in[7];
    const float* blk_cw  = (const float*)d_in[8];
    const float* blk_cb  = (const float*)d_in[9];
    const float* blk_xpw = (const float*)d_in[10];
    const float* blk_dtw = (const float*)d_in[11];
    const float* blk_dtb = (const float*)d_in[12];
    const float* blk_Alog= (const float*)d_in[13];
    const float* blk_D   = (const float*)d_in[14];
    const float* blk_opw = (const float*)d_in[15];
    const float* op_w   = (const float*)d_in[16];
    const float* op_b   = (const float*)d_in[17];
    const float* cls_w  = (const float*)d_in[18];
    const float* cls_b  = (const float*)d_in[19];
    float* out = (float*)d_out;

    const int BL = 4096;
    float* ws = (float*)d_ws;
    float* hn   = ws;                    // BL*256
    float* h0   = hn + (size_t)BL * 256; // BL*256
    float* h2   = h0 + (size_t)BL * 256; // BL*256
    float* xz   = h2 + (size_t)BL * 256; // BL*1024
    float* uc   = xz + (size_t)BL * 1024;// BL*512
    float* xdbc = uc + (size_t)BL * 512; // BL*48
    float* dlt  = xdbc + (size_t)BL * 48;// BL*512
    float* yb   = dlt + (size_t)BL * 512;// BL*512

    dim3 blk(256);

    // 1. hn = x @ in_w.T + in_b   (M=4096, N=256, K=768)
    gemm_bt<<<dim3(256 / 64, BL / 64), blk, 0, stream>>>(x, 768, in_w, in_b, nullptr, hn, BL, 256, 768, 0);
    // 2. h0 = gelu(LN(hn))
    ln_act<<<BL, 256, 0, stream>>>(hn, ln_g, ln_b, h0, 1);

    for (int l = 0; l < 2; l++) {
        const float* ng   = blk_ng  + l * 256;
        const float* nb   = blk_nb  + l * 256;
        const float* ipw  = blk_ipw + (size_t)l * 1024 * 256;
        const float* cw   = blk_cw  + (size_t)l * 512 * 4;
        const float* cb   = blk_cb  + l * 512;
        const float* xpw  = blk_xpw + (size_t)l * 48 * 512;
        const float* dtw  = blk_dtw + (size_t)l * 512 * 16;
        const float* dtb  = blk_dtb + l * 512;
        const float* Alog = blk_Alog+ (size_t)l * 512 * 16;
        const float* Dl   = blk_D   + l * 512;
        const float* opw  = blk_opw + (size_t)l * 256 * 512;

        // hn = LN(h0)
        ln_act<<<BL, 256, 0, stream>>>(h0, ng, nb, hn, 0);
        // xz = hn @ ipw.T   (N=1024, K=256)
        gemm_bt<<<dim3(1024 / 64, BL / 64), blk, 0, stream>>>(hn, 256, ipw, nullptr, nullptr, xz, BL, 1024, 256, 0);
        // uc = silu(conv(u) + cb)
        conv_silu<<<(BL * 512 + 255) / 256, blk, 0, stream>>>(xz, cw, cb, uc);
        // xdbc = uc @ xpw.T  (N=48, K=512)
        gemm_bt<<<dim3(1, BL / 64), blk, 0, stream>>>(uc, 512, xpw, nullptr, nullptr, xdbc, BL, 48, 512, 0);
        // dlt = softplus(dt @ dtw.T + dtb)  (N=512, K=16, A cols 0..15 of xdbc, lda=48)
        gemm_bt<<<dim3(512 / 64, BL / 64), blk, 0, stream>>>(xdbc, 48, dtw, dtb, nullptr, dlt, BL, 512, 16, 2);
        // chunked scan -> yb (fused +u*D and *silu(z))
        scan_chunked<<<512, 1024, 0, stream>>>(dlt, uc, xdbc, xz, Alog, Dl, yb);
        // h0 = h0 + yb @ opw.T  (N=256, K=512)
        gemm_bt<<<dim3(256 / 64, BL / 64), blk, 0, stream>>>(yb, 512, opw, nullptr, h0, h0, BL, 256, 512, 0);
    }

    // h2 = gelu(h0 @ op_w.T + op_b)
    gemm_bt<<<dim3(256 / 64, BL / 64), blk, 0, stream>>>(h0, 256, op_w, op_b, nullptr, h2, BL, 256, 256, 1);
    // logits = h2 @ cls_w.T + cls_b  -> d_out
    gemm_bt<<<dim3(128 / 64, BL / 64), blk, 0, stream>>>(h2, 256, cls_w, cls_b, nullptr, out, BL, 128, 256, 0);
    // l2 scalar
    zero_one<<<1, 1, 0, stream>>>(out + (size_t)BL * 128);
    l2_kernel<<<BL, 256, 0, stream>>>(h2, out + (size_t)BL * 128);
}

// Round 3
// 494.806 us; speedup vs baseline: 4.1905x; 1.7876x over previous
//
#include <hip/hip_runtime.h>
#include <hip/hip_bf16.h>
#include <math.h>

typedef __attribute__((ext_vector_type(8))) short frag8;   // 8 bf16 (4 VGPRs)
typedef __attribute__((ext_vector_type(4))) float f32x4;

// ---------------- device helpers ----------------
__device__ __forceinline__ float gelu_exact(float x) {
    return 0.5f * x * (1.0f + erff(x * 0.70710678118654752f));
}
__device__ __forceinline__ float softplus_f(float x) {
    return (x > 20.0f) ? x : log1pf(expf(x));
}
__device__ __forceinline__ float sigmoid_f(float x) {
    return 1.0f / (1.0f + __expf(-x));
}
__device__ __forceinline__ unsigned short bf16bits(float x) {
    __hip_bfloat16 h = __float2bfloat16(x);
    return *(unsigned short*)&h;
}

// ---------------- fused fp32 -> bf16 conversion (x + 6 weight tensors) --------
struct CvtArgs {
    const float* src[7];
    unsigned short* dst[7];
    int n4[7];   // element count / 4 per segment
};
__global__ __launch_bounds__(256)
void cvt_all(CvtArgs a, int total4)
{
    int i = blockIdx.x * 256 + threadIdx.x;
    if (i >= total4) return;
    int seg = 0;
    while (i >= a.n4[seg]) { i -= a.n4[seg]; seg++; }
    float4 v = reinterpret_cast<const float4*>(a.src[seg])[i];
    ushort4 o;
    o.x = bf16bits(v.x); o.y = bf16bits(v.y); o.z = bf16bits(v.z); o.w = bf16bits(v.w);
    reinterpret_cast<ushort4*>(a.dst[seg])[i] = o;
}

// ---------------- MFMA bf16 GEMM ----------------
// C[m,n] = act(sum_k A[m,k]*W[n,k] + bias[n]) + res[m,n]
// A: M x K bf16 (lda = K), W: N x K bf16 packed. C fp32 (always), Cb bf16 shadow (optional).
// Tile 64x64, 4 waves, each wave a 32x32 quadrant via 2x2 mfma_f32_16x16x32_bf16.
// act: 0 none, 1 gelu
__global__ __launch_bounds__(256)
void gemm_mfma(const unsigned short* __restrict__ A,
               const unsigned short* __restrict__ W,
               const float* __restrict__ bias,
               const float* res,
               float* __restrict__ C,
               unsigned short* Cb,
               int N, int K, int act)
{
    __shared__ __align__(16) unsigned short As[64][40];  // 32-k tile + 8 pad
    __shared__ __align__(16) unsigned short Bs[64][40];

    const int tid = threadIdx.x;
    const int wid = tid >> 6, lane = tid & 63;
    const int wm = (wid >> 1) * 32, wn = (wid & 1) * 32;
    const int m0 = blockIdx.y * 64, n0 = blockIdx.x * 64;
    const int lrow = lane & 15, quad = lane >> 4;

    const int sm = tid >> 2;           // staging row 0..63
    const int sk = (tid & 3) * 8;      // staging k-offset {0,8,16,24}

    f32x4 acc[2][2] = {};

    for (int k0 = 0; k0 < K; k0 += 32) {
        // stage A tile (64 x 32)
        float4 av = *reinterpret_cast<const float4*>(A + (size_t)(m0 + sm) * K + k0 + sk);
        *reinterpret_cast<float4*>(&As[sm][sk]) = av;
        // stage B tile (64 x 32) from W (N x K), zero-pad n >= N
        float4 bv = {0.f, 0.f, 0.f, 0.f};
        int n = n0 + sm;
        if (n < N) bv = *reinterpret_cast<const float4*>(W + (size_t)n * K + k0 + sk);
        *reinterpret_cast<float4*>(&Bs[sm][sk]) = bv;
        __syncthreads();

        frag8 a0 = *reinterpret_cast<const frag8*>(&As[wm + lrow][quad * 8]);
        frag8 a1 = *reinterpret_cast<const frag8*>(&As[wm + 16 + lrow][quad * 8]);
        frag8 b0 = *reinterpret_cast<const frag8*>(&Bs[wn + lrow][quad * 8]);
        frag8 b1 = *reinterpret_cast<const frag8*>(&Bs[wn + 16 + lrow][quad * 8]);

        acc[0][0] = __builtin_amdgcn_mfma_f32_16x16x32_bf16(a0, b0, acc[0][0], 0, 0, 0);
        acc[0][1] = __builtin_amdgcn_mfma_f32_16x16x32_bf16(a0, b1, acc[0][1], 0, 0, 0);
        acc[1][0] = __builtin_amdgcn_mfma_f32_16x16x32_bf16(a1, b0, acc[1][0], 0, 0, 0);
        acc[1][1] = __builtin_amdgcn_mfma_f32_16x16x32_bf16(a1, b1, acc[1][1], 0, 0, 0);
        __syncthreads();
    }

    // epilogue: C/D layout col = lane&15, row = quad*4 + r
    #pragma unroll
    for (int mi = 0; mi < 2; mi++) {
        #pragma unroll
        for (int nj = 0; nj < 2; nj++) {
            int col = n0 + wn + nj * 16 + lrow;
            if (col >= N) continue;
            #pragma unroll
            for (int r = 0; r < 4; r++) {
                int row = m0 + wm + mi * 16 + quad * 4 + r;
                float v = acc[mi][nj][r];
                if (bias) v += bias[col];
                if (act == 1) v = gelu_exact(v);
                if (res) v += res[(size_t)row * N + col];
                C[(size_t)row * N + col] = v;
                if (Cb) Cb[(size_t)row * N + col] = bf16bits(v);
            }
        }
    }
}

// ---------------- LayerNorm over last dim (=256) ----------------
__global__ __launch_bounds__(256)
void ln_act(const float* __restrict__ in, const float* __restrict__ g,
            const float* __restrict__ b, float* outf, unsigned short* outb, int act)
{
    __shared__ float s1[256];
    __shared__ float s2[256];
    const int row = blockIdx.x, tid = threadIdx.x;
    float v = in[(size_t)row * 256 + tid];
    s1[tid] = v;
    s2[tid] = v * v;
    __syncthreads();
    for (int off = 128; off > 0; off >>= 1) {
        if (tid < off) { s1[tid] += s1[tid + off]; s2[tid] += s2[tid + off]; }
        __syncthreads();
    }
    float mu = s1[0] * (1.0f / 256.0f);
    float var = s2[0] * (1.0f / 256.0f) - mu * mu;
    float o = (v - mu) * rsqrtf(var + 1e-5f) * g[tid] + b[tid];
    if (act) o = gelu_exact(o);
    if (outf) outf[(size_t)row * 256 + tid] = o;
    if (outb) outb[(size_t)row * 256 + tid] = bf16bits(o);
}

// ---------------- causal depthwise conv (D_CONV=4) + bias + SiLU ----------------
__global__ void conv_silu(const float* __restrict__ xz, const float* __restrict__ cw,
                          const float* __restrict__ cb, float* __restrict__ uc,
                          unsigned short* __restrict__ ucb)
{
    int idx = blockIdx.x * blockDim.x + threadIdx.x;
    if (idx >= 4096 * 512) return;
    int d = idx & 511;
    int bt = idx >> 9;
    int t = bt & 1023, b = bt >> 10;
    float acc = cb[d];
    #pragma unroll
    for (int k = 0; k < 4; k++) {
        int tt = t - 3 + k;
        if (tt >= 0) acc += xz[((size_t)(b * 1024 + tt)) * 1024 + d] * cw[d * 4 + k];
    }
    float o = acc * sigmoid_f(acc);
    uc[idx] = o;
    ucb[idx] = bf16bits(o);
}

// ---------------- dt projection (K=16) + softplus ----------------
// dlt[bt][d] = softplus(sum_k xdbc[bt][k]*dtw[d][k] + dtb[d])
__global__ __launch_bounds__(256)
void dt_softplus(const float* __restrict__ xdbc, const float* __restrict__ dtw,
                 const float* __restrict__ dtb, float* __restrict__ dlt)
{
    __shared__ float dts[16];
    const int bt = blockIdx.x, tid = threadIdx.x;
    if (tid < 16) dts[tid] = xdbc[(size_t)bt * 48 + tid];
    __syncthreads();
    #pragma unroll
    for (int rep = 0; rep < 2; rep++) {
        int d = tid + rep * 256;
        float acc = dtb[d];
        #pragma unroll
        for (int k = 0; k < 16; k++) acc += dts[k] * dtw[d * 16 + k];
        dlt[(size_t)bt * 512 + d] = softplus_f(acc);
    }
}

// ---------------- chunked selective scan (bf16 y out, XCD-swizzled) ------------
__global__ __launch_bounds__(1024)
void scan_chunked(const float* __restrict__ delta, const float* __restrict__ uc,
                  const float* __restrict__ xdbc, const float* __restrict__ xz,
                  const float* __restrict__ A_log, const float* __restrict__ Dp,
                  unsigned short* __restrict__ y)
{
    __shared__ float aprod_s[16][64];
    __shared__ float sfin_s[16][64];
    __shared__ float sin_s[16][64];
    __shared__ float ylocal[16][64][4];

    // XCD swizzle: physical j -> logical so 64 consecutive d-group blocks share an XCD
    const int j = blockIdx.x;
    const int bid = (j & 7) * 64 + (j >> 3);
    const int b = bid >> 7;
    const int d0 = (bid & 127) * 4;
    const int w = threadIdx.x >> 6;
    const int lane = threadIdx.x & 63;
    const int dsub = lane >> 4, s = lane & 15;
    const int d = d0 + dsub;

    const float Acoef = -__expf(A_log[d * 16 + s]);
    const float Dd = Dp[d];

    const size_t row0 = (size_t)b * 1024 + w * 64;
    const float* pd = delta + row0 * 512 + d;
    const float* pu = uc    + row0 * 512 + d;
    const float* pB = xdbc  + row0 * 48 + 16 + s;
    const float* pC = xdbc  + row0 * 48 + 32 + s;

    float st = 0.0f, ap = 1.0f;
    #pragma unroll 4
    for (int t = 0; t < 64; t++) {
        float dt = pd[(size_t)t * 512];
        float ut = pu[(size_t)t * 512];
        float Bt = pB[(size_t)t * 48];
        float Ct = pC[(size_t)t * 48];
        float dA = __expf(dt * Acoef);
        st = st * dA + dt * ut * Bt;
        ap *= dA;
        float part = st * Ct;
        part += __shfl_xor(part, 8, 16);
        part += __shfl_xor(part, 4, 16);
        part += __shfl_xor(part, 2, 16);
        part += __shfl_xor(part, 1, 16);
        if (s == 0) ylocal[w][t][dsub] = part;
    }
    aprod_s[w][lane] = ap;
    sfin_s[w][lane] = st;
    __syncthreads();

    if (w == 0) {
        float pre = 0.0f;
        #pragma unroll
        for (int c = 0; c < 16; c++) {
            sin_s[c][lane] = pre;
            pre = sfin_s[c][lane] + aprod_s[c][lane] * pre;
        }
    }
    __syncthreads();

    float g = sin_s[w][lane];
    const float* pz = xz + row0 * 1024 + 512 + d;
    unsigned short* py = y + row0 * 512 + d;
    #pragma unroll 4
    for (int t = 0; t < 64; t++) {
        float dt = pd[(size_t)t * 512];
        float Ct = pC[(size_t)t * 48];
        g *= __expf(dt * Acoef);
        float part = g * Ct;
        part += __shfl_xor(part, 8, 16);
        part += __shfl_xor(part, 4, 16);
        part += __shfl_xor(part, 2, 16);
        part += __shfl_xor(part, 1, 16);
        if (s == 0) {
            float ut = pu[(size_t)t * 512];
            float zt = pz[(size_t)t * 1024];
            float yv = ylocal[w][t][dsub] + part + ut * Dd;
            py[(size_t)t * 512] = bf16bits(yv * (zt * sigmoid_f(zt)));
        }
    }
}

// ---------------- l2 loss ----------------
__global__ void zero_one(float* p) { if (threadIdx.x == 0 && blockIdx.x == 0) *p = 0.0f; }

__global__ __launch_bounds__(256)
void l2_kernel(const float* __restrict__ h, float* out)
{
    __shared__ float s1[256];
    const int row = blockIdx.x, tid = threadIdx.x;
    float v = h[(size_t)row * 256 + tid];
    s1[tid] = v * v;
    __syncthreads();
    for (int off = 128; off > 0; off >>= 1) {
        if (tid < off) s1[tid] += s1[tid + off];
        __syncthreads();
    }
    if (tid == 0) atomicAdd(out, sqrtf(s1[0]) * (0.01f / 4096.0f));
}

// ---------------- launcher ----------------
extern "C" void kernel_launch(void* const* d_in, const int* in_sizes, int n_in,
                              void* d_out, int out_size, void* d_ws, size_t ws_size,
                              hipStream_t stream)
{
    const float* x      = (const float*)d_in[0];
    const float* in_w   = (const float*)d_in[1];
    const float* in_b   = (const float*)d_in[2];
    const float* ln_g   = (const float*)d_in[3];
    const float* ln_b   = (const float*)d_in[4];
    const float* blk_ng  = (const float*)d_in[5];
    const float* blk_nb  = (const float*)d_in[6];
    const float* blk_cw  = (const float*)d_in[8];
    const float* blk_cb  = (const float*)d_in[9];
    const float* blk_dtw = (const float*)d_in[11];
    const float* blk_dtb = (const float*)d_in[12];
    const float* blk_Alog= (const float*)d_in[13];
    const float* blk_D   = (const float*)d_in[14];
    const float* op_b   = (const float*)d_in[17];
    const float* cls_b  = (const float*)d_in[19];
    float* out = (float*)d_out;

    const int BL = 4096;
    float* ws = (float*)d_ws;
    // fp32 buffers
    float* hn   = ws;                         // 1,048,576  (also h2 at the end)
    float* h0   = hn + 1048576;               // 1,048,576
    float* xz   = h0 + 1048576;               // 4,194,304
    float* uc   = xz + 4194304;               // 2,097,152
    float* xdbc = uc + 2097152;               //   196,608
    float* dlt  = xdbc + 196608;              // 2,097,152 (region also hosts xb / ucb bf16)
    float* h2   = hn;                         // alias: hn dead after initial LN
    // bf16 buffers
    unsigned short* wb  = (unsigned short*)(dlt + 2097152);
    unsigned short* hnb = wb + 1130496;       // 1,048,576 (alias h0b)
    unsigned short* ybb = hnb + 1048576;      // 2,097,152 (alias h2b)
    unsigned short* xb  = (unsigned short*)dlt;   // 3,145,728 elems, dead before conv
    unsigned short* ucb = (unsigned short*)dlt;   // 2,097,152 elems, dead before dt_softplus
    unsigned short* h0b = hnb;
    unsigned short* h2b = ybb;
    // weight slices inside wb
    unsigned short* in_wb  = wb;               // 196,608
    unsigned short* ipw_b  = wb + 196608;      // 524,288 (2 layers)
    unsigned short* xpw_b  = wb + 720896;      //  49,152
    unsigned short* opw_b  = wb + 770048;      // 262,144
    unsigned short* op_wb  = wb + 1032192;     //  65,536
    unsigned short* cls_wb = wb + 1097728;     //  32,768

    // ---- fp32 -> bf16 conversions (x + all GEMM weights) ----
    CvtArgs ca;
    ca.src[0] = x;                  ca.dst[0] = xb;     ca.n4[0] = 3145728 / 4;
    ca.src[1] = (const float*)d_in[1];  ca.dst[1] = in_wb;  ca.n4[1] = 196608 / 4;
    ca.src[2] = (const float*)d_in[7];  ca.dst[2] = ipw_b;  ca.n4[2] = 524288 / 4;
    ca.src[3] = (const float*)d_in[10]; ca.dst[3] = xpw_b;  ca.n4[3] = 49152 / 4;
    ca.src[4] = (const float*)d_in[15]; ca.dst[4] = opw_b;  ca.n4[4] = 262144 / 4;
    ca.src[5] = (const float*)d_in[16]; ca.dst[5] = op_wb;  ca.n4[5] = 65536 / 4;
    ca.src[6] = (const float*)d_in[18]; ca.dst[6] = cls_wb; ca.n4[6] = 32768 / 4;
    int total4 = (3145728 + 1130496) / 4;
    cvt_all<<<(total4 + 255) / 256, 256, 0, stream>>>(ca, total4);

    // 1. hn = x @ in_w.T + in_b   (N=256, K=768)
    gemm_mfma<<<dim3(4, 64), 256, 0, stream>>>(xb, in_wb, in_b, nullptr, hn, nullptr, 256, 768, 0);
    // 2. h0 = gelu(LN(hn))
    ln_act<<<BL, 256, 0, stream>>>(hn, ln_g, ln_b, h0, nullptr, 1);

    for (int l = 0; l < 2; l++) {
        const float* ng   = blk_ng  + l * 256;
        const float* nb   = blk_nb  + l * 256;
        const float* cw   = blk_cw  + (size_t)l * 512 * 4;
        const float* cb   = blk_cb  + l * 512;
        const float* dtw  = blk_dtw + (size_t)l * 512 * 16;
        const float* dtb  = blk_dtb + l * 512;
        const float* Alog = blk_Alog+ (size_t)l * 512 * 16;
        const float* Dl   = blk_D   + l * 512;
        const unsigned short* ipwl = ipw_b + (size_t)l * 262144;
        const unsigned short* xpwl = xpw_b + (size_t)l * 24576;
        const unsigned short* opwl = opw_b + (size_t)l * 131072;

        // hnb = LN(h0) in bf16
        ln_act<<<BL, 256, 0, stream>>>(h0, ng, nb, nullptr, hnb, 0);
        // xz = hnb @ ipw.T   (N=1024, K=256)
        gemm_mfma<<<dim3(16, 64), 256, 0, stream>>>(hnb, ipwl, nullptr, nullptr, xz, nullptr, 1024, 256, 0);
        // uc, ucb = silu(conv(u) + cb)
        conv_silu<<<(BL * 512 + 255) / 256, 256, 0, stream>>>(xz, cw, cb, uc, ucb);
        // xdbc = ucb @ xpw.T  (N=48, K=512)
        gemm_mfma<<<dim3(1, 64), 256, 0, stream>>>(ucb, xpwl, nullptr, nullptr, xdbc, nullptr, 48, 512, 0);
        // dlt = softplus(dt @ dtw.T + dtb)
        dt_softplus<<<BL, 256, 0, stream>>>(xdbc, dtw, dtb, dlt);
        // scan -> ybb (bf16, fused +u*D and *silu(z))
        scan_chunked<<<512, 1024, 0, stream>>>(dlt, uc, xdbc, xz, Alog, Dl, ybb);
        // h0 = h0 + ybb @ opw.T  (N=256, K=512); also h0b shadow
        gemm_mfma<<<dim3(4, 64), 256, 0, stream>>>(ybb, opwl, nullptr, h0, h0, h0b, 256, 512, 0);
    }

    // h2 = gelu(h0b @ op_w.T + op_b); h2b shadow
    gemm_mfma<<<dim3(4, 64), 256, 0, stream>>>(h0b, op_wb, op_b, nullptr, h2, h2b, 256, 256, 1);
    // logits = h2b @ cls_w.T + cls_b -> d_out (N=128, K=256)
    gemm_mfma<<<dim3(2, 64), 256, 0, stream>>>(h2b, cls_wb, cls_b, nullptr, out, nullptr, 128, 256, 0);
    // l2 scalar
    zero_one<<<1, 1, 0, stream>>>(out + (size_t)BL * 128);
    l2_kernel<<<BL, 256, 0, stream>>>(h2, out + (size_t)BL * 128);
}

// Round 4
// 436.303 us; speedup vs baseline: 4.7524x; 1.1341x over previous
//
#include <hip/hip_runtime.h>
#include <hip/hip_bf16.h>
#include <math.h>

typedef __attribute__((ext_vector_type(8))) short frag8;   // 8 bf16 (4 VGPRs)
typedef __attribute__((ext_vector_type(4))) float f32x4;

// ---------------- device helpers ----------------
__device__ __forceinline__ float gelu_exact(float x) {
    return 0.5f * x * (1.0f + erff(x * 0.70710678118654752f));
}
__device__ __forceinline__ float softplus_f(float x) {
    return (x > 20.0f) ? x : log1pf(expf(x));
}
__device__ __forceinline__ float sigmoid_f(float x) {
    return 1.0f / (1.0f + __expf(-x));
}
__device__ __forceinline__ unsigned short bf16bits(float x) {
    __hip_bfloat16 h = __float2bfloat16(x);
    return *(unsigned short*)&h;
}
// sum over the 16 lanes of each DPP row (lane&15 varies, lane>>4 fixed) — VALU-pipe only
__device__ __forceinline__ float row_sum16(float x) {
    int t;
    t = __builtin_amdgcn_update_dpp(0, __builtin_bit_cast(int, x), 0x128, 0xf, 0xf, true); // row_ror:8
    x += __builtin_bit_cast(float, t);
    t = __builtin_amdgcn_update_dpp(0, __builtin_bit_cast(int, x), 0x124, 0xf, 0xf, true); // row_ror:4
    x += __builtin_bit_cast(float, t);
    t = __builtin_amdgcn_update_dpp(0, __builtin_bit_cast(int, x), 0x122, 0xf, 0xf, true); // row_ror:2
    x += __builtin_bit_cast(float, t);
    t = __builtin_amdgcn_update_dpp(0, __builtin_bit_cast(int, x), 0x121, 0xf, 0xf, true); // row_ror:1
    x += __builtin_bit_cast(float, t);
    return x;
}

// ---------------- fused fp32 -> bf16 conversion ----------------
struct CvtArgs {
    const float* src[7];
    unsigned short* dst[7];
    int n4[7];
};
__global__ __launch_bounds__(256)
void cvt_all(CvtArgs a, int total4)
{
    int i = blockIdx.x * 256 + threadIdx.x;
    if (i >= total4) return;
    int seg = 0;
    while (i >= a.n4[seg]) { i -= a.n4[seg]; seg++; }
    float4 v = reinterpret_cast<const float4*>(a.src[seg])[i];
    ushort4 o;
    o.x = bf16bits(v.x); o.y = bf16bits(v.y); o.z = bf16bits(v.z); o.w = bf16bits(v.w);
    reinterpret_cast<ushort4*>(a.dst[seg])[i] = o;
}

// ---------------- generic MFMA bf16 GEMM (64x64 tile) ----------------
__global__ __launch_bounds__(256)
void gemm_mfma(const unsigned short* __restrict__ A,
               const unsigned short* __restrict__ W,
               const float* __restrict__ bias,
               const float* res,
               float* __restrict__ C,
               unsigned short* Cb,
               int N, int K, int act)
{
    __shared__ __align__(16) unsigned short As[64][40];
    __shared__ __align__(16) unsigned short Bs[64][40];

    const int tid = threadIdx.x;
    const int wid = tid >> 6, lane = tid & 63;
    const int wm = (wid >> 1) * 32, wn = (wid & 1) * 32;
    const int m0 = blockIdx.y * 64, n0 = blockIdx.x * 64;
    const int lrow = lane & 15, quad = lane >> 4;

    const int sm = tid >> 2;
    const int sk = (tid & 3) * 8;

    f32x4 acc[2][2] = {};

    for (int k0 = 0; k0 < K; k0 += 32) {
        float4 av = *reinterpret_cast<const float4*>(A + (size_t)(m0 + sm) * K + k0 + sk);
        *reinterpret_cast<float4*>(&As[sm][sk]) = av;
        float4 bv = {0.f, 0.f, 0.f, 0.f};
        int n = n0 + sm;
        if (n < N) bv = *reinterpret_cast<const float4*>(W + (size_t)n * K + k0 + sk);
        *reinterpret_cast<float4*>(&Bs[sm][sk]) = bv;
        __syncthreads();

        frag8 a0 = *reinterpret_cast<const frag8*>(&As[wm + lrow][quad * 8]);
        frag8 a1 = *reinterpret_cast<const frag8*>(&As[wm + 16 + lrow][quad * 8]);
        frag8 b0 = *reinterpret_cast<const frag8*>(&Bs[wn + lrow][quad * 8]);
        frag8 b1 = *reinterpret_cast<const frag8*>(&Bs[wn + 16 + lrow][quad * 8]);

        acc[0][0] = __builtin_amdgcn_mfma_f32_16x16x32_bf16(a0, b0, acc[0][0], 0, 0, 0);
        acc[0][1] = __builtin_amdgcn_mfma_f32_16x16x32_bf16(a0, b1, acc[0][1], 0, 0, 0);
        acc[1][0] = __builtin_amdgcn_mfma_f32_16x16x32_bf16(a1, b0, acc[1][0], 0, 0, 0);
        acc[1][1] = __builtin_amdgcn_mfma_f32_16x16x32_bf16(a1, b1, acc[1][1], 0, 0, 0);
        __syncthreads();
    }

    #pragma unroll
    for (int mi = 0; mi < 2; mi++) {
        #pragma unroll
        for (int nj = 0; nj < 2; nj++) {
            int col = n0 + wn + nj * 16 + lrow;
            if (col >= N) continue;
            #pragma unroll
            for (int r = 0; r < 4; r++) {
                int row = m0 + wm + mi * 16 + quad * 4 + r;
                float v = acc[mi][nj][r];
                if (bias) v += bias[col];
                if (act == 1) v = gelu_exact(v);
                if (res) v += res[(size_t)row * N + col];
                C[(size_t)row * N + col] = v;
                if (Cb) Cb[(size_t)row * N + col] = bf16bits(v);
            }
        }
    }
}

// ---------------- full-row GEMM (N=256) with fused LN / GELU / residual / L2 ----
// Tile 16(m) x 256(n). 4 waves; wave w owns cols [64w, 64w+64).
// v = acc + bias? + res?; if g1: v=LN1(v)*g1+b1 (then gelu1?); elif gelu1: gelu(v);
// outF? store fp32; l2out? add 0.01/4096*||row||; if g2: outB=bf16(LN2(v)); elif outB: bf16(v)
__global__ __launch_bounds__(256)
void rowgemm(const unsigned short* __restrict__ A,
             const unsigned short* __restrict__ W,
             const float* __restrict__ bias,
             const float* res,
             const float* g1, const float* b1, int gelu1,
             const float* g2, const float* b2,
             float* outF, unsigned short* outB, float* l2out, int K)
{
    __shared__ __align__(16) unsigned short As[16][40];
    __shared__ __align__(16) unsigned short Bs[256][40];
    __shared__ float red[4][16][2];
    __shared__ float sq[16];

    const int tid = threadIdx.x;
    const int w = tid >> 6, lane = tid & 63;
    const int lrow = lane & 15, quad = lane >> 4;
    const int m0 = blockIdx.x * 16;

    f32x4 acc[4] = {};

    for (int k0 = 0; k0 < K; k0 += 32) {
        if (tid < 64) {
            float4 av = *reinterpret_cast<const float4*>(A + (size_t)(m0 + (tid >> 2)) * K + k0 + (tid & 3) * 8);
            *reinterpret_cast<float4*>(&As[tid >> 2][(tid & 3) * 8]) = av;
        }
        #pragma unroll
        for (int i = 0; i < 4; i++) {
            int n = (tid >> 2) + i * 64;
            float4 bv = *reinterpret_cast<const float4*>(W + (size_t)n * K + k0 + (tid & 3) * 8);
            *reinterpret_cast<float4*>(&Bs[n][(tid & 3) * 8]) = bv;
        }
        __syncthreads();
        frag8 a = *reinterpret_cast<const frag8*>(&As[lrow][quad * 8]);
        #pragma unroll
        for (int nj = 0; nj < 4; nj++) {
            frag8 b = *reinterpret_cast<const frag8*>(&Bs[w * 64 + nj * 16 + lrow][quad * 8]);
            acc[nj] = __builtin_amdgcn_mfma_f32_16x16x32_bf16(a, b, acc[nj], 0, 0, 0);
        }
        __syncthreads();
    }

    // materialize v[nj][r]; row = m0 + quad*4 + r, col = w*64 + nj*16 + lrow
    float v[4][4];
    #pragma unroll
    for (int nj = 0; nj < 4; nj++) {
        int col = w * 64 + nj * 16 + lrow;
        #pragma unroll
        for (int r = 0; r < 4; r++) {
            int row = m0 + quad * 4 + r;
            float t = acc[nj][r];
            if (bias) t += bias[col];
            if (res) t += res[(size_t)row * 256 + col];
            v[nj][r] = t;
        }
    }

    // ---- optional LN1 ----
    if (g1) {
        #pragma unroll
        for (int r = 0; r < 4; r++) {
            float s1 = v[0][r] + v[1][r] + v[2][r] + v[3][r];
            float s2 = v[0][r]*v[0][r] + v[1][r]*v[1][r] + v[2][r]*v[2][r] + v[3][r]*v[3][r];
            s1 = row_sum16(s1); s2 = row_sum16(s2);
            if (lrow == 0) { red[w][quad * 4 + r][0] = s1; red[w][quad * 4 + r][1] = s2; }
        }
        __syncthreads();
        #pragma unroll
        for (int r = 0; r < 4; r++) {
            int rr = quad * 4 + r;
            float t1 = red[0][rr][0] + red[1][rr][0] + red[2][rr][0] + red[3][rr][0];
            float t2 = red[0][rr][1] + red[1][rr][1] + red[2][rr][1] + red[3][rr][1];
            float mu = t1 * (1.0f / 256.0f);
            float var = t2 * (1.0f / 256.0f) - mu * mu;
            float rstd = rsqrtf(var + 1e-5f);
            #pragma unroll
            for (int nj = 0; nj < 4; nj++) {
                int col = w * 64 + nj * 16 + lrow;
                float t = (v[nj][r] - mu) * rstd * g1[col] + b1[col];
                if (gelu1) t = gelu_exact(t);
                v[nj][r] = t;
            }
        }
        __syncthreads();
    } else if (gelu1) {
        #pragma unroll
        for (int nj = 0; nj < 4; nj++)
            #pragma unroll
            for (int r = 0; r < 4; r++)
                v[nj][r] = gelu_exact(v[nj][r]);
    }

    if (outF) {
        #pragma unroll
        for (int nj = 0; nj < 4; nj++) {
            int col = w * 64 + nj * 16 + lrow;
            #pragma unroll
            for (int r = 0; r < 4; r++)
                outF[(size_t)(m0 + quad * 4 + r) * 256 + col] = v[nj][r];
        }
    }

    // ---- optional L2 row-norm accumulation ----
    if (l2out) {
        #pragma unroll
        for (int r = 0; r < 4; r++) {
            float s2 = v[0][r]*v[0][r] + v[1][r]*v[1][r] + v[2][r]*v[2][r] + v[3][r]*v[3][r];
            s2 = row_sum16(s2);
            if (lrow == 0) red[w][quad * 4 + r][0] = s2;
        }
        __syncthreads();
        if (tid < 16) {
            float t = red[0][tid][0] + red[1][tid][0] + red[2][tid][0] + red[3][tid][0];
            sq[tid] = sqrtf(t);
        }
        __syncthreads();
        if (tid == 0) {
            float a = 0.f;
            #pragma unroll
            for (int i = 0; i < 16; i++) a += sq[i];
            atomicAdd(l2out, a * (0.01f / 4096.0f));
        }
    }

    // ---- optional LN2 -> bf16, or plain bf16 shadow ----
    if (g2) {
        __syncthreads();
        #pragma unroll
        for (int r = 0; r < 4; r++) {
            float s1 = v[0][r] + v[1][r] + v[2][r] + v[3][r];
            float s2 = v[0][r]*v[0][r] + v[1][r]*v[1][r] + v[2][r]*v[2][r] + v[3][r]*v[3][r];
            s1 = row_sum16(s1); s2 = row_sum16(s2);
            if (lrow == 0) { red[w][quad * 4 + r][0] = s1; red[w][quad * 4 + r][1] = s2; }
        }
        __syncthreads();
        #pragma unroll
        for (int r = 0; r < 4; r++) {
            int rr = quad * 4 + r;
            float t1 = red[0][rr][0] + red[1][rr][0] + red[2][rr][0] + red[3][rr][0];
            float t2 = red[0][rr][1] + red[1][rr][1] + red[2][rr][1] + red[3][rr][1];
            float mu = t1 * (1.0f / 256.0f);
            float var = t2 * (1.0f / 256.0f) - mu * mu;
            float rstd = rsqrtf(var + 1e-5f);
            #pragma unroll
            for (int nj = 0; nj < 4; nj++) {
                int col = w * 64 + nj * 16 + lrow;
                outB[(size_t)(m0 + rr) * 256 + col] = bf16bits((v[nj][r] - mu) * rstd * g2[col] + b2[col]);
            }
        }
    } else if (outB) {
        #pragma unroll
        for (int nj = 0; nj < 4; nj++) {
            int col = w * 64 + nj * 16 + lrow;
            #pragma unroll
            for (int r = 0; r < 4; r++)
                outB[(size_t)(m0 + quad * 4 + r) * 256 + col] = bf16bits(v[nj][r]);
        }
    }
}

// ---------------- causal depthwise conv (D_CONV=4) + bias + SiLU ----------------
__global__ void conv_silu(const float* __restrict__ xz, const float* __restrict__ cw,
                          const float* __restrict__ cb, float* __restrict__ uc,
                          unsigned short* __restrict__ ucb)
{
    int idx = blockIdx.x * blockDim.x + threadIdx.x;
    if (idx >= 4096 * 512) return;
    int d = idx & 511;
    int bt = idx >> 9;
    int t = bt & 1023, b = bt >> 10;
    float acc = cb[d];
    #pragma unroll
    for (int k = 0; k < 4; k++) {
        int tt = t - 3 + k;
        if (tt >= 0) acc += xz[((size_t)(b * 1024 + tt)) * 1024 + d] * cw[d * 4 + k];
    }
    float o = acc * sigmoid_f(acc);
    uc[idx] = o;
    ucb[idx] = bf16bits(o);
}

// ---------------- dt projection (K=16) + softplus ----------------
__global__ __launch_bounds__(256)
void dt_softplus(const float* __restrict__ xdbc, const float* __restrict__ dtw,
                 const float* __restrict__ dtb, float* __restrict__ dlt)
{
    __shared__ float dts[16];
    const int bt = blockIdx.x, tid = threadIdx.x;
    if (tid < 16) dts[tid] = xdbc[(size_t)bt * 48 + tid];
    __syncthreads();
    #pragma unroll
    for (int rep = 0; rep < 2; rep++) {
        int d = tid + rep * 256;
        float acc = dtb[d];
        #pragma unroll
        for (int k = 0; k < 16; k++) acc += dts[k] * dtw[d * 16 + k];
        dlt[(size_t)bt * 512 + d] = softplus_f(acc);
    }
}

// ---------------- chunked selective scan (DPP reduce, bf16 out, XCD-swizzled) ---
__global__ __launch_bounds__(1024)
void scan_chunked(const float* __restrict__ delta, const float* __restrict__ uc,
                  const float* __restrict__ xdbc, const float* __restrict__ xz,
                  const float* __restrict__ A_log, const float* __restrict__ Dp,
                  unsigned short* __restrict__ y)
{
    __shared__ float aprod_s[16][64];
    __shared__ float sfin_s[16][64];
    __shared__ float sin_s[16][64];
    __shared__ float ylocal[16][64][4];

    const int j = blockIdx.x;
    const int bid = (j & 7) * 64 + (j >> 3);
    const int b = bid >> 7;
    const int d0 = (bid & 127) * 4;
    const int w = threadIdx.x >> 6;
    const int lane = threadIdx.x & 63;
    const int dsub = lane >> 4, s = lane & 15;
    const int d = d0 + dsub;

    const float Acoef = -__expf(A_log[d * 16 + s]);
    const float Dd = Dp[d];

    const size_t row0 = (size_t)b * 1024 + w * 64;
    const float* pd = delta + row0 * 512 + d;
    const float* pu = uc    + row0 * 512 + d;
    const float* pB = xdbc  + row0 * 48 + 16 + s;
    const float* pC = xdbc  + row0 * 48 + 32 + s;

    float st = 0.0f, ap = 1.0f;
    #pragma unroll 8
    for (int t = 0; t < 64; t++) {
        float dt = pd[(size_t)t * 512];
        float ut = pu[(size_t)t * 512];
        float Bt = pB[(size_t)t * 48];
        float Ct = pC[(size_t)t * 48];
        float dA = __expf(dt * Acoef);
        st = st * dA + dt * ut * Bt;
        ap *= dA;
        float part = row_sum16(st * Ct);
        if (s == 0) ylocal[w][t][dsub] = part;
    }
    aprod_s[w][lane] = ap;
    sfin_s[w][lane] = st;
    __syncthreads();

    if (w == 0) {
        float pre = 0.0f;
        #pragma unroll
        for (int c = 0; c < 16; c++) {
            sin_s[c][lane] = pre;
            pre = sfin_s[c][lane] + aprod_s[c][lane] * pre;
        }
    }
    __syncthreads();

    float g = sin_s[w][lane];
    const float* pz = xz + row0 * 1024 + 512 + d;
    unsigned short* py = y + row0 * 512 + d;
    #pragma unroll 8
    for (int t = 0; t < 64; t++) {
        float dt = pd[(size_t)t * 512];
        float Ct = pC[(size_t)t * 48];
        g *= __expf(dt * Acoef);
        float part = row_sum16(g * Ct);
        if (s == 0) {
            float ut = pu[(size_t)t * 512];
            float zt = pz[(size_t)t * 1024];
            float yv = ylocal[w][t][dsub] + part + ut * Dd;
            py[(size_t)t * 512] = bf16bits(yv * (zt * sigmoid_f(zt)));
        }
    }
}

// ---------------- misc ----------------
__global__ void zero_one(float* p) { if (threadIdx.x == 0 && blockIdx.x == 0) *p = 0.0f; }

// ---------------- launcher ----------------
extern "C" void kernel_launch(void* const* d_in, const int* in_sizes, int n_in,
                              void* d_out, int out_size, void* d_ws, size_t ws_size,
                              hipStream_t stream)
{
    const float* x      = (const float*)d_in[0];
    const float* in_b   = (const float*)d_in[2];
    const float* ln_g   = (const float*)d_in[3];
    const float* ln_b   = (const float*)d_in[4];
    const float* blk_ng  = (const float*)d_in[5];
    const float* blk_nb  = (const float*)d_in[6];
    const float* blk_cw  = (const float*)d_in[8];
    const float* blk_cb  = (const float*)d_in[9];
    const float* blk_dtw = (const float*)d_in[11];
    const float* blk_dtb = (const float*)d_in[12];
    const float* blk_Alog= (const float*)d_in[13];
    const float* blk_D   = (const float*)d_in[14];
    const float* op_b   = (const float*)d_in[17];
    const float* cls_b  = (const float*)d_in[19];
    float* out = (float*)d_out;

    const int BL = 4096;
    float* ws = (float*)d_ws;
    float* hn   = ws;                         // 1,048,576 (spare)
    float* h0   = hn + 1048576;               // 1,048,576
    float* xz   = h0 + 1048576;               // 4,194,304
    float* uc   = xz + 4194304;               // 2,097,152
    float* xdbc = uc + 2097152;               //   196,608
    float* dlt  = xdbc + 196608;              // 2,097,152
    unsigned short* wb  = (unsigned short*)(dlt + 2097152);
    unsigned short* hnb = wb + 1130496;       // 1,048,576
    unsigned short* ybb = hnb + 1048576;      // 2,097,152
    unsigned short* xb  = (unsigned short*)dlt;   // x bf16 (dead before dlt written)
    unsigned short* ucb = (unsigned short*)dlt;   // uc bf16 (dead before dlt written)
    unsigned short* h0b = hnb;
    unsigned short* h2b = ybb;
    unsigned short* in_wb  = wb;
    unsigned short* ipw_b  = wb + 196608;
    unsigned short* xpw_b  = wb + 720896;
    unsigned short* opw_b  = wb + 770048;
    unsigned short* op_wb  = wb + 1032192;
    unsigned short* cls_wb = wb + 1097728;

    CvtArgs ca;
    ca.src[0] = x;                  ca.dst[0] = xb;     ca.n4[0] = 3145728 / 4;
    ca.src[1] = (const float*)d_in[1];  ca.dst[1] = in_wb;  ca.n4[1] = 196608 / 4;
    ca.src[2] = (const float*)d_in[7];  ca.dst[2] = ipw_b;  ca.n4[2] = 524288 / 4;
    ca.src[3] = (const float*)d_in[10]; ca.dst[3] = xpw_b;  ca.n4[3] = 49152 / 4;
    ca.src[4] = (const float*)d_in[15]; ca.dst[4] = opw_b;  ca.n4[4] = 262144 / 4;
    ca.src[5] = (const float*)d_in[16]; ca.dst[5] = op_wb;  ca.n4[5] = 65536 / 4;
    ca.src[6] = (const float*)d_in[18]; ca.dst[6] = cls_wb; ca.n4[6] = 32768 / 4;
    int total4 = (3145728 + 1130496) / 4;
    cvt_all<<<(total4 + 255) / 256, 256, 0, stream>>>(ca, total4);
    zero_one<<<1, 1, 0, stream>>>(out + (size_t)BL * 128);

    // in_proj + bias + LN(ln) + GELU -> h0 (fp32), + LN(layer0) -> hnb (bf16)
    rowgemm<<<256, 256, 0, stream>>>(xb, in_wb, in_b, nullptr,
                                     ln_g, ln_b, 1,
                                     blk_ng, blk_nb,
                                     h0, hnb, nullptr, 768);

    for (int l = 0; l < 2; l++) {
        const float* cw   = blk_cw  + (size_t)l * 512 * 4;
        const float* cb   = blk_cb  + l * 512;
        const float* dtw  = blk_dtw + (size_t)l * 512 * 16;
        const float* dtb  = blk_dtb + l * 512;
        const float* Alog = blk_Alog+ (size_t)l * 512 * 16;
        const float* Dl   = blk_D   + l * 512;
        const unsigned short* ipwl = ipw_b + (size_t)l * 262144;
        const unsigned short* xpwl = xpw_b + (size_t)l * 24576;
        const unsigned short* opwl = opw_b + (size_t)l * 131072;

        // xz = hnb @ ipw.T   (N=1024, K=256)
        gemm_mfma<<<dim3(16, 64), 256, 0, stream>>>(hnb, ipwl, nullptr, nullptr, xz, nullptr, 1024, 256, 0);
        // uc, ucb = silu(conv(u) + cb)
        conv_silu<<<(BL * 512 + 255) / 256, 256, 0, stream>>>(xz, cw, cb, uc, ucb);
        // xdbc = ucb @ xpw.T  (N=48, K=512)
        gemm_mfma<<<dim3(1, 64), 256, 0, stream>>>(ucb, xpwl, nullptr, nullptr, xdbc, nullptr, 48, 512, 0);
        // dlt = softplus(dt @ dtw.T + dtb)
        dt_softplus<<<BL, 256, 0, stream>>>(xdbc, dtw, dtb, dlt);
        // scan -> ybb
        scan_chunked<<<512, 1024, 0, stream>>>(dlt, uc, xdbc, xz, Alog, Dl, ybb);
        // h0 += ybb @ opw.T; layer0: +LN(layer1)->hnb; layer1: ->h0b bf16 only
        if (l == 0)
            rowgemm<<<256, 256, 0, stream>>>(ybb, opwl, nullptr, h0,
                                             nullptr, nullptr, 0,
                                             blk_ng + 256, blk_nb + 256,
                                             h0, hnb, nullptr, 512);
        else
            rowgemm<<<256, 256, 0, stream>>>(ybb, opwl, nullptr, h0,
                                             nullptr, nullptr, 0,
                                             nullptr, nullptr,
                                             nullptr, h0b, nullptr, 512);
    }

    // h2 = gelu(h0b @ op_w.T + op_b) -> h2b (bf16) + fused L2 scalar
    rowgemm<<<256, 256, 0, stream>>>(h0b, op_wb, op_b, nullptr,
                                     nullptr, nullptr, 1,
                                     nullptr, nullptr,
                                     nullptr, h2b, out + (size_t)BL * 128, 256);
    // logits = h2b @ cls_w.T + cls_b -> d_out (N=128, K=256)
    gemm_mfma<<<dim3(2, 64), 256, 0, stream>>>(h2b, cls_wb, cls_b, nullptr, out, nullptr, 128, 256, 0);
}